// Round 2
// baseline (356.719 us; speedup 1.0000x reference)
//
#include <hip/hip_runtime.h>

constexpr int NN = 100000;   // nodes
constexpr int NE = 1600000;  // edges
constexpr int NF = 64;       // input features
constexpr int NH = 16;       // hidden
constexpr int SCAN_BLK = 256;
constexpr int NB1 = (NN + SCAN_BLK - 1) / SCAN_BLK;  // 391 partial blocks

// Kernel 1: per node n: p[n,:] = x[n,:] @ Wl1 ; r[n,:] = x[n,:] @ Wr1
__global__ __launch_bounds__(256)
void k1_node_lin(const float* __restrict__ x,
                 const float* __restrict__ Wl1,
                 const float* __restrict__ Wr1,
                 float* __restrict__ p,
                 float* __restrict__ r)
{
    __shared__ float sW[2 * NF * NH];   // Wl1 | Wr1, row-major [k][j]
    for (int i = threadIdx.x; i < NF * NH; i += 256) {
        sW[i]           = Wl1[i];
        sW[NF * NH + i] = Wr1[i];
    }
    __syncthreads();

    int n = blockIdx.x * 256 + threadIdx.x;
    if (n >= NN) return;

    float aL[NH], aR[NH];
#pragma unroll
    for (int j = 0; j < NH; ++j) { aL[j] = 0.f; aR[j] = 0.f; }

    const float4* xr = reinterpret_cast<const float4*>(x + (size_t)n * NF);
#pragma unroll
    for (int k4 = 0; k4 < NF / 4; ++k4) {
        float4 v = xr[k4];
        float xs[4] = {v.x, v.y, v.z, v.w};
#pragma unroll
        for (int t = 0; t < 4; ++t) {
            const float* wl = &sW[(k4 * 4 + t) * NH];
            const float* wr = &sW[NF * NH + (k4 * 4 + t) * NH];
#pragma unroll
            for (int j = 0; j < NH; ++j) {
                aL[j] = fmaf(xs[t], wl[j], aL[j]);
                aR[j] = fmaf(xs[t], wr[j], aR[j]);
            }
        }
    }

    float4* pp = reinterpret_cast<float4*>(p + (size_t)n * NH);
    float4* rp = reinterpret_cast<float4*>(r + (size_t)n * NH);
#pragma unroll
    for (int j4 = 0; j4 < NH / 4; ++j4) {
        pp[j4] = make_float4(aL[j4*4], aL[j4*4+1], aL[j4*4+2], aL[j4*4+3]);
        rp[j4] = make_float4(aR[j4*4], aR[j4*4+1], aR[j4*4+2], aR[j4*4+3]);
    }
}

// Histogram of kept in-degrees.
__global__ __launch_bounds__(256)
void k_hist(const int* __restrict__ ei, const float* __restrict__ As,
            const float* __restrict__ ws, int* __restrict__ deg)
{
    int e = blockIdx.x * 256 + threadIdx.x;
    if (e >= NE) return;
    float ewm = ws[0] * As[e] + ws[1] * As[NE + e];
    if (ewm == 0.0f) return;
    atomicAdd(&deg[ei[NE + e]], 1);
}

// Scan stage 1: per-block sums of deg.
__global__ __launch_bounds__(SCAN_BLK)
void k_scan_partial(const int* __restrict__ deg, int* __restrict__ bsum)
{
    __shared__ int s[SCAN_BLK];
    int idx = blockIdx.x * SCAN_BLK + threadIdx.x;
    s[threadIdx.x] = (idx < NN) ? deg[idx] : 0;
    __syncthreads();
    for (int off = SCAN_BLK / 2; off > 0; off >>= 1) {
        if (threadIdx.x < off) s[threadIdx.x] += s[threadIdx.x + off];
        __syncthreads();
    }
    if (threadIdx.x == 0) bsum[blockIdx.x] = s[0];
}

// Scan stage 2: single-block exclusive scan of the NB1 block sums.
__global__ __launch_bounds__(512)
void k_scan_sums(const int* __restrict__ bsum, int* __restrict__ boff,
                 int* __restrict__ offsets)
{
    __shared__ int s[512];
    int t = threadIdx.x;
    int v = (t < NB1) ? bsum[t] : 0;
    s[t] = v;
    __syncthreads();
    for (int off = 1; off < 512; off <<= 1) {
        int u = (t >= off) ? s[t - off] : 0;
        __syncthreads();
        s[t] += u;
        __syncthreads();
    }
    if (t < NB1) boff[t] = s[t] - v;          // exclusive block offset
    if (t == 511) offsets[NN] = s[511];       // total kept edges
}

// Scan stage 3: per-block exclusive scan + block offset -> offsets, cursors.
__global__ __launch_bounds__(SCAN_BLK)
void k_scan_final(const int* __restrict__ deg, const int* __restrict__ boff,
                  int* __restrict__ offsets, int* __restrict__ cursors)
{
    __shared__ int s[SCAN_BLK];
    int idx = blockIdx.x * SCAN_BLK + threadIdx.x;
    int v = (idx < NN) ? deg[idx] : 0;
    s[threadIdx.x] = v;
    __syncthreads();
    for (int off = 1; off < SCAN_BLK; off <<= 1) {
        int u = (threadIdx.x >= off) ? s[threadIdx.x - off] : 0;
        __syncthreads();
        s[threadIdx.x] += u;
        __syncthreads();
    }
    if (idx < NN) {
        int ex = boff[blockIdx.x] + s[threadIdx.x] - v;
        offsets[idx] = ex;
        cursors[idx] = ex;
    }
}

// Fill CSR: slot allocation via per-node cursor.
__global__ __launch_bounds__(256)
void k_build(const int* __restrict__ ei, const float* __restrict__ As,
             const float* __restrict__ ws, int* __restrict__ cursors,
             int* __restrict__ csr_src)
{
    int e = blockIdx.x * 256 + threadIdx.x;
    if (e >= NE) return;
    float ewm = ws[0] * As[e] + ws[1] * As[NE + e];
    if (ewm == 0.0f) return;
    int slot = atomicAdd(&cursors[ei[NE + e]], 1);
    csr_src[slot] = ei[e];
}

// Layer-1 aggregation by gather (16 lanes per node) + fused epilogue:
// h = relu(sum_in p[src] + r[n] + bl1); q[n] = h.Wl2; out[n] = h.Wr2 + bl2
__global__ __launch_bounds__(256)
void k_agg1(const int* __restrict__ offsets, const int* __restrict__ csr_src,
            const float* __restrict__ p, const float* __restrict__ r,
            const float* __restrict__ bl1, const float* __restrict__ Wl2,
            const float* __restrict__ bl2, const float* __restrict__ Wr2,
            float* __restrict__ q, float* __restrict__ out)
{
    int g = blockIdx.x * 256 + threadIdx.x;
    int n = g >> 4, k = g & 15;
    if (n >= NN) return;

    int beg = offsets[n], end = offsets[n + 1];
    float acc = 0.f;
    for (int i = beg; i < end; ++i) {
        int s = csr_src[i];                 // 16 lanes same addr -> broadcast
        acc += p[(size_t)s * NH + k];       // 64 B contiguous line per edge
    }
    float h = acc + r[(size_t)n * NH + k] + bl1[k];
    h = h > 0.f ? h : 0.f;
    float qv = h * Wl2[k];
    float sv = h * Wr2[k];
#pragma unroll
    for (int m = 8; m >= 1; m >>= 1) {      // xor masks <16 stay in the group
        qv += __shfl_xor(qv, m);
        sv += __shfl_xor(sv, m);
    }
    if (k == 0) {
        q[n]   = qv;
        out[n] = sv + bl2[0];
    }
}

// Layer-2 aggregation by gather: out[n] += sum_in q[src]
__global__ __launch_bounds__(256)
void k_agg2(const int* __restrict__ offsets, const int* __restrict__ csr_src,
            const float* __restrict__ q, float* __restrict__ out)
{
    int n = blockIdx.x * 256 + threadIdx.x;
    if (n >= NN) return;
    int beg = offsets[n], end = offsets[n + 1];
    float acc = 0.f;
    for (int i = beg; i < end; ++i)
        acc += q[csr_src[i]];
    out[n] += acc;
}

extern "C" void kernel_launch(void* const* d_in, const int* in_sizes, int n_in,
                              void* d_out, int out_size, void* d_ws, size_t ws_size,
                              hipStream_t stream)
{
    const float* x   = (const float*)d_in[0];
    const int*   ei  = (const int*)  d_in[1];
    const float* As  = (const float*)d_in[2];
    const float* ws  = (const float*)d_in[3];
    const float* Wl1 = (const float*)d_in[4];
    const float* bl1 = (const float*)d_in[5];
    const float* Wr1 = (const float*)d_in[6];
    const float* Wl2 = (const float*)d_in[7];
    const float* bl2 = (const float*)d_in[8];
    const float* Wr2 = (const float*)d_in[9];
    float* out = (float*)d_out;

    // workspace layout (~21 MB total)
    float* p       = (float*)d_ws;                    // NN*NH
    float* r       = p + (size_t)NN * NH;             // NN*NH
    float* q       = r + (size_t)NN * NH;             // NN
    int*   deg     = (int*)(q + NN);                  // NN
    int*   offsets = deg + NN;                        // NN+1
    int*   cursors = offsets + NN + 1;                // NN
    int*   bsum    = cursors + NN;                    // NB1
    int*   boff    = bsum + NB1;                      // NB1
    int*   csr_src = boff + NB1;                      // NE

    hipMemsetAsync(deg, 0, NN * sizeof(int), stream);

    k1_node_lin<<<(NN + 255) / 256, 256, 0, stream>>>(x, Wl1, Wr1, p, r);

    k_hist<<<(NE + 255) / 256, 256, 0, stream>>>(ei, As, ws, deg);
    k_scan_partial<<<NB1, SCAN_BLK, 0, stream>>>(deg, bsum);
    k_scan_sums<<<1, 512, 0, stream>>>(bsum, boff, offsets);
    k_scan_final<<<NB1, SCAN_BLK, 0, stream>>>(deg, boff, offsets, cursors);
    k_build<<<(NE + 255) / 256, 256, 0, stream>>>(ei, As, ws, cursors, csr_src);

    long long t1 = (long long)NN * NH;
    k_agg1<<<(int)((t1 + 255) / 256), 256, 0, stream>>>(offsets, csr_src, p, r,
                                                        bl1, Wl2, bl2, Wr2, q, out);
    k_agg2<<<(NN + 255) / 256, 256, 0, stream>>>(offsets, csr_src, q, out);
}